// Round 3
// baseline (946.122 us; speedup 1.0000x reference)
//
#include <hip/hip_runtime.h>
#include <hip/hip_bf16.h>

typedef __bf16 bf16;
typedef __bf16 bf16x8 __attribute__((ext_vector_type(8)));
typedef __bf16 bf16x4 __attribute__((ext_vector_type(4)));
typedef float f32x4 __attribute__((ext_vector_type(4)));

#define S_LEN 2048
#define D_MODEL 1024
#define N_HEADS 16
#define D_HEAD 64
#define M_ROWS 4096   // B*S

// ---------------- f32 -> bf16 cast (vectorized) ----------------
__global__ void cvt_f32_bf16(const float* __restrict__ in, bf16* __restrict__ out, int n) {
    int i = (blockIdx.x * blockDim.x + threadIdx.x) * 4;
    int stride = gridDim.x * blockDim.x * 4;
    for (; i < n; i += stride) {
        f32x4 v = *(const f32x4*)(in + i);
        bf16x4 o;
        o[0] = (bf16)v[0]; o[1] = (bf16)v[1]; o[2] = (bf16)v[2]; o[3] = (bf16)v[3];
        *(bf16x4*)(out + i) = o;
    }
}

// ---------------- f32 [K][N] -> bf16 [N][K] transpose-convert ----------------
__global__ void cvtT_f32_bf16(const float* __restrict__ in, bf16* __restrict__ out) {
    __shared__ float t[32][33];
    int k0 = blockIdx.x * 32, n0 = blockIdx.y * 32;
    int lr = threadIdx.x & 31, lc = threadIdx.x >> 5;
#pragma unroll
    for (int p = 0; p < 4; ++p)
        t[lc + p * 8][lr] = in[(size_t)(k0 + lc + p * 8) * D_MODEL + n0 + lr];
    __syncthreads();
#pragma unroll
    for (int p = 0; p < 4; ++p)
        out[(size_t)(n0 + lc + p * 8) * D_MODEL + k0 + lr] = (bf16)t[lr][lc + p * 8];
}

// ---------------- bf16 GEMM: C[M,N] = A[M,K] @ Bt[N,K]^T + bias ----------------
// mode 0: bf16 split-head [B,H,S,DH]; mode 1: f32 row-major; mode 2: bf16 [B,H,DH,S]
__global__ __launch_bounds__(256) void gemm_bf16(
    const bf16* __restrict__ A, const bf16* __restrict__ Bt,
    const float* __restrict__ bias, bf16* __restrict__ outh,
    float* __restrict__ outf, int mode) {
    const int K = D_MODEL;
    __shared__ bf16 Als[128][80];
    __shared__ bf16 Bls[128][80];
    const int tid = threadIdx.x;
    const int lane = tid & 63, wave = tid >> 6;
    const int wm = wave >> 1, wn = wave & 1;
    const int g = lane >> 4, r16 = lane & 15;
    const int m0 = blockIdx.x * 128, n0 = blockIdx.y * 128;
    const int srow = tid >> 3, scol = (tid & 7) * 8;
    f32x4 acc[4][4] = {};
    for (int kt = 0; kt < K; kt += 64) {
        __syncthreads();
#pragma unroll
        for (int p = 0; p < 4; ++p) {
            int row = p * 32 + srow;
            *(bf16x8*)&Als[row][scol] = *(const bf16x8*)(A + (size_t)(m0 + row) * K + kt + scol);
            *(bf16x8*)&Bls[row][scol] = *(const bf16x8*)(Bt + (size_t)(n0 + row) * K + kt + scol);
        }
        __syncthreads();
#pragma unroll
        for (int kk = 0; kk < 2; ++kk) {
            bf16x8 af[4], bfr[4];
#pragma unroll
            for (int i = 0; i < 4; ++i) af[i] = *(const bf16x8*)&Als[wm * 64 + i * 16 + r16][kk * 32 + g * 8];
#pragma unroll
            for (int j = 0; j < 4; ++j) bfr[j] = *(const bf16x8*)&Bls[wn * 64 + j * 16 + r16][kk * 32 + g * 8];
#pragma unroll
            for (int i = 0; i < 4; ++i)
#pragma unroll
                for (int j = 0; j < 4; ++j)
                    acc[i][j] = __builtin_amdgcn_mfma_f32_16x16x32_bf16(af[i], bfr[j], acc[i][j], 0, 0, 0);
        }
    }
#pragma unroll
    for (int i = 0; i < 4; ++i) {
#pragma unroll
        for (int j = 0; j < 4; ++j) {
            int col = n0 + wn * 64 + j * 16 + r16;
            float bv = bias[col];
#pragma unroll
            for (int r = 0; r < 4; ++r) {
                int row = m0 + wm * 64 + i * 16 + g * 4 + r;
                float v = acc[i][j][r] + bv;
                if (mode == 0) {
                    int b = row >> 11, s = row & (S_LEN - 1);
                    int h = col >> 6, dh = col & 63;
                    outh[(size_t)(((b * N_HEADS + h) * S_LEN) + s) * D_HEAD + dh] = (bf16)v;
                } else if (mode == 1) {
                    outf[(size_t)row * D_MODEL + col] = v;
                } else {
                    int b = row >> 11, s = row & (S_LEN - 1);
                    int h = col >> 6, dh = col & 63;
                    outh[(((size_t)(b * N_HEADS + h)) * D_HEAD + dh) * S_LEN + s] = (bf16)v;
                }
            }
        }
    }
}

// ---------------- single-pass fused causal attention ----------------
// grid: 1-D, 32 qx-slots x 32 bh. block: 256 (4 waves x 16 q-rows).
// Writes unnormalized exp(S) to attn, accumulates rowsum + PV, then fused
// normalize + zero sweep over its own 64-row strip.
__global__ __launch_bounds__(256) void attn_fused(
    const bf16* __restrict__ Qh, const bf16* __restrict__ Kh, const bf16* __restrict__ VT,
    float* __restrict__ attn, bf16* __restrict__ ctx) {
    const int S = S_LEN, DH = D_HEAD;
    __shared__ bf16 Kls[64][80];
    __shared__ bf16 Vls[64][80];     // V^T tile: [dh][kj]
    __shared__ bf16 Pls[4][16][80];  // per-wave P tile
    __shared__ float rowinv[64];
    const int tid = threadIdx.x;
    const int lane = tid & 63, w = tid >> 6;
    const int g = lane >> 4, r16 = lane & 15;
    // balanced qt assignment: 4-term constant-sum permutation, heavy first
    const int id = blockIdx.x;
    const int bh = id & 31;
    const int qx = id >> 5;
    const int a = qx & 7, kq = qx >> 3;
    const int qt = (kq == 0) ? (31 - a) : (kq == 1) ? (16 + a) : (kq == 2) ? (15 - a) : a;
    const int q0 = qt * 64;

    // Q fragments: row = q0 + w*16 + r16, dh = kk*32 + g*8 .. +7
    bf16x8 qa[2];
#pragma unroll
    for (int kk = 0; kk < 2; ++kk)
        qa[kk] = *(const bf16x8*)(Qh + (size_t)(bh * S + q0 + w * 16 + r16) * DH + kk * 32 + g * 8);

    float rs[4] = {0.f, 0.f, 0.f, 0.f};
    f32x4 oacc[4] = {};
    for (int kt = 0; kt <= qt; ++kt) {
        __syncthreads();
#pragma unroll
        for (int sIt = 0; sIt < 2; ++sIt) {
            int slot = tid + sIt * 256;
            int srow = slot >> 3, c8 = (slot & 7) * 8;
            *(bf16x8*)&Kls[srow][c8] =
                *(const bf16x8*)(Kh + (size_t)(bh * S + kt * 64 + srow) * DH + c8);
            *(bf16x8*)&Vls[srow][c8] =
                *(const bf16x8*)(VT + ((size_t)bh * DH + srow) * S + kt * 64 + c8);
        }
        __syncthreads();
        // QK^T + exp + store unnormalized + stage P
#pragma unroll
        for (int n = 0; n < 4; ++n) {
            f32x4 s = {0.f, 0.f, 0.f, 0.f};
#pragma unroll
            for (int kk = 0; kk < 2; ++kk) {
                bf16x8 kb = *(const bf16x8*)&Kls[n * 16 + r16][kk * 32 + g * 8];
                s = __builtin_amdgcn_mfma_f32_16x16x32_bf16(qa[kk], kb, s, 0, 0, 0);
            }
            int col = kt * 64 + n * 16 + r16;
#pragma unroll
            for (int r = 0; r < 4; ++r) {
                int row = q0 + w * 16 + g * 4 + r;
                float p = (col <= row) ? __expf(s[r] * 0.125f) : 0.f;
                rs[r] += p;
                attn[(size_t)(bh * S + row) * S + col] = p;
                Pls[w][g * 4 + r][n * 16 + r16] = (bf16)p;
            }
        }
        // PV: oacc[d] += P(16x64) @ V(64x64); B^T = V^T = Vls
#pragma unroll
        for (int d = 0; d < 4; ++d) {
#pragma unroll
            for (int kk = 0; kk < 2; ++kk) {
                bf16x8 pa = *(const bf16x8*)&Pls[w][r16][kk * 32 + g * 8];
                bf16x8 vb = *(const bf16x8*)&Vls[d * 16 + r16][kk * 32 + g * 8];
                oacc[d] = __builtin_amdgcn_mfma_f32_16x16x32_bf16(pa, vb, oacc[d], 0, 0, 0);
            }
        }
    }
    // reduce row sums over the 16 col-lanes
#pragma unroll
    for (int r = 0; r < 4; ++r) {
        rs[r] += __shfl_xor(rs[r], 1);
        rs[r] += __shfl_xor(rs[r], 2);
        rs[r] += __shfl_xor(rs[r], 4);
        rs[r] += __shfl_xor(rs[r], 8);
    }
    float inv[4];
#pragma unroll
    for (int r = 0; r < 4; ++r) inv[r] = 1.f / rs[r];
    if (r16 == 0) {
#pragma unroll
        for (int r = 0; r < 4; ++r) rowinv[w * 16 + g * 4 + r] = inv[r];
    }
    // ctx write, normalized: [B*S, D] bf16
    const int b = bh >> 4, h = bh & 15;
#pragma unroll
    for (int d = 0; d < 4; ++d) {
#pragma unroll
        for (int r = 0; r < 4; ++r) {
            int srowg = q0 + w * 16 + g * 4 + r;
            ctx[(size_t)(b * S + srowg) * D_MODEL + h * D_HEAD + d * 16 + r16] =
                (bf16)(oacc[d][r] * inv[r]);
        }
    }
    __syncthreads();
    // normalize + zero sweep over own strip: 4 threads/row, interleaved 16B chunks
    {
        int rr = tid >> 2, q4 = (tid & 3) * 4;
        int row = q0 + rr;
        float sc = rowinv[rr];
        float* prow = attn + (size_t)(bh * S + row) * S;
        int limit = row + 1;  // cols [0, limit) scaled; rest zero
        for (int c = q4; c < S; c += 16) {
            if (c + 4 <= limit) {
                f32x4 v = *(f32x4*)(prow + c);
                v *= sc;
                *(f32x4*)(prow + c) = v;
            } else if (c >= limit) {
                f32x4 z = {0.f, 0.f, 0.f, 0.f};
                *(f32x4*)(prow + c) = z;
            } else {
#pragma unroll
                for (int e = 0; e < 4; ++e)
                    prow[c + e] = (c + e < limit) ? prow[c + e] * sc : 0.f;
            }
        }
    }
}

extern "C" void kernel_launch(void* const* d_in, const int* in_sizes, int n_in,
                              void* d_out, int out_size, void* d_ws, size_t ws_size,
                              hipStream_t stream) {
    const float* query = (const float*)d_in[0];
    const float* key   = (const float*)d_in[1];
    const float* value = (const float*)d_in[2];
    const float* Wq = (const float*)d_in[4];
    const float* bq = (const float*)d_in[5];
    const float* Wk = (const float*)d_in[6];
    const float* bk = (const float*)d_in[7];
    const float* Wv = (const float*)d_in[8];
    const float* bv = (const float*)d_in[9];
    const float* Wo = (const float*)d_in[10];
    const float* bo = (const float*)d_in[11];

    float* out  = (float*)d_out;                       // [4096,1024]
    float* attn = out + (size_t)M_ROWS * D_MODEL;      // [2,16,2048,2048]

    bf16* ws  = (bf16*)d_ws;
    const size_t MD = (size_t)M_ROWS * D_MODEL;   // 4M elems
    const size_t DD = (size_t)D_MODEL * D_MODEL;  // 1M elems
    bf16* Xq  = ws;
    bf16* Xk  = Xq + MD;
    bf16* Xv  = Xk + MD;
    bf16* WqT = Xv + MD;
    bf16* WkT = WqT + DD;
    bf16* WvT = WkT + DD;
    bf16* WoT = WvT + DD;
    bf16* Qh  = WoT + DD;
    bf16* Kh  = Qh + MD;
    bf16* VT  = Kh + MD;
    bf16* Ctx = VT + MD;

    int n = (int)MD;
    cvt_f32_bf16<<<2048, 256, 0, stream>>>(query, Xq, n);
    cvt_f32_bf16<<<2048, 256, 0, stream>>>(key, Xk, n);
    cvt_f32_bf16<<<2048, 256, 0, stream>>>(value, Xv, n);
    dim3 tg(32, 32);
    cvtT_f32_bf16<<<tg, 256, 0, stream>>>(Wq, WqT);
    cvtT_f32_bf16<<<tg, 256, 0, stream>>>(Wk, WkT);
    cvtT_f32_bf16<<<tg, 256, 0, stream>>>(Wv, WvT);
    cvtT_f32_bf16<<<tg, 256, 0, stream>>>(Wo, WoT);

    dim3 gg(M_ROWS / 128, D_MODEL / 128);
    gemm_bf16<<<gg, 256, 0, stream>>>(Xq, WqT, bq, Qh, nullptr, 0);
    gemm_bf16<<<gg, 256, 0, stream>>>(Xk, WkT, bk, Kh, nullptr, 0);
    gemm_bf16<<<gg, 256, 0, stream>>>(Xv, WvT, bv, VT, nullptr, 2);

    attn_fused<<<1024, 256, 0, stream>>>(Qh, Kh, VT, attn, Ctx);

    gemm_bf16<<<gg, 256, 0, stream>>>(Ctx, WoT, bo, nullptr, out, 1);
}

// Round 6
// 806.486 us; speedup vs baseline: 1.1731x; 1.1731x over previous
//
#include <hip/hip_runtime.h>
#include <hip/hip_bf16.h>

typedef __bf16 bf16;
typedef __bf16 bf16x8 __attribute__((ext_vector_type(8)));
typedef __bf16 bf16x4 __attribute__((ext_vector_type(4)));
typedef float f32x4 __attribute__((ext_vector_type(4)));

#define S_LEN 2048
#define D_MODEL 1024
#define N_HEADS 16
#define D_HEAD 64
#define M_ROWS 4096   // B*S

__device__ __forceinline__ void async_copy16(void* lds, const void* g) {
    __builtin_amdgcn_global_load_lds(
        (const __attribute__((address_space(1))) unsigned int*)g,
        (__attribute__((address_space(3))) unsigned int*)lds, 16, 0, 0);
}

// ---------------- f32 -> bf16 cast (vectorized) ----------------
__global__ void cvt_f32_bf16(const float* __restrict__ in, bf16* __restrict__ out, int n) {
    int i = (blockIdx.x * blockDim.x + threadIdx.x) * 4;
    int stride = gridDim.x * blockDim.x * 4;
    for (; i < n; i += stride) {
        f32x4 v = *(const f32x4*)(in + i);
        bf16x4 o;
        o[0] = (bf16)v[0]; o[1] = (bf16)v[1]; o[2] = (bf16)v[2]; o[3] = (bf16)v[3];
        *(bf16x4*)(out + i) = o;
    }
}

// ---------------- f32 [K][N] -> bf16 [N][K] transpose-convert ----------------
__global__ void cvtT_f32_bf16(const float* __restrict__ in, bf16* __restrict__ out) {
    __shared__ float t[32][33];
    int k0 = blockIdx.x * 32, n0 = blockIdx.y * 32;
    int lr = threadIdx.x & 31, lc = threadIdx.x >> 5;
#pragma unroll
    for (int p = 0; p < 4; ++p)
        t[lc + p * 8][lr] = in[(size_t)(k0 + lc + p * 8) * D_MODEL + n0 + lr];
    __syncthreads();
#pragma unroll
    for (int p = 0; p < 4; ++p)
        out[(size_t)(n0 + lc + p * 8) * D_MODEL + k0 + lr] = (bf16)t[lr][lc + p * 8];
}

// ---------------- bf16 GEMM (m97-style: global_load_lds, linear LDS) ----------------
// C[M,N] = A[M,K] @ Bt[N,K]^T + bias
// mode 0: bf16 split-head [B,H,S,DH]; mode 1: f32 row-major; mode 2: bf16 [B,H,DH,S]
__global__ __launch_bounds__(256) void gemm_bf16(
    const bf16* __restrict__ A, const bf16* __restrict__ Bt,
    const float* __restrict__ bias, bf16* __restrict__ outh,
    float* __restrict__ outf, int mode) {
    const int K = D_MODEL;
    __shared__ bf16 Als[128][64];
    __shared__ bf16 Bls[128][64];
    const int tid = threadIdx.x;
    const int lane = tid & 63, wave = tid >> 6;
    const int wm = wave >> 1, wn = wave & 1;
    const int g = lane >> 4, r16 = lane & 15;
    const int m0 = blockIdx.x * 128, n0 = blockIdx.y * 128;
    // staging: 16 chunks of 1KB per matrix; chunk = 8 rows of 128B
    const int crow = lane >> 3;          // row within chunk
    const int ccol = (lane & 7) * 8;     // elem col within row
    f32x4 acc[4][4] = {};
    for (int kt = 0; kt < K; kt += 64) {
        __syncthreads();
#pragma unroll
        for (int i = 0; i < 4; ++i) {
            int c = wave * 4 + i;        // chunk 0..15
            int row = c * 8 + crow;
            async_copy16(&Als[c * 8][0], A + (size_t)(m0 + row) * K + kt + ccol);
            async_copy16(&Bls[c * 8][0], Bt + (size_t)(n0 + row) * K + kt + ccol);
        }
        __syncthreads();
#pragma unroll
        for (int kk = 0; kk < 2; ++kk) {
            bf16x8 af[4], bfr[4];
#pragma unroll
            for (int i = 0; i < 4; ++i) af[i] = *(const bf16x8*)&Als[wm * 64 + i * 16 + r16][kk * 32 + g * 8];
#pragma unroll
            for (int j = 0; j < 4; ++j) bfr[j] = *(const bf16x8*)&Bls[wn * 64 + j * 16 + r16][kk * 32 + g * 8];
#pragma unroll
            for (int i = 0; i < 4; ++i)
#pragma unroll
                for (int j = 0; j < 4; ++j)
                    acc[i][j] = __builtin_amdgcn_mfma_f32_16x16x32_bf16(af[i], bfr[j], acc[i][j], 0, 0, 0);
        }
    }
#pragma unroll
    for (int i = 0; i < 4; ++i) {
#pragma unroll
        for (int j = 0; j < 4; ++j) {
            int col = n0 + wn * 64 + j * 16 + r16;
            float bv = bias[col];
#pragma unroll
            for (int r = 0; r < 4; ++r) {
                int row = m0 + wm * 64 + i * 16 + g * 4 + r;
                float v = acc[i][j][r] + bv;
                if (mode == 0) {
                    int b = row >> 11, s = row & (S_LEN - 1);
                    int h = col >> 6, dh = col & 63;
                    outh[(size_t)(((b * N_HEADS + h) * S_LEN) + s) * D_HEAD + dh] = (bf16)v;
                } else if (mode == 1) {
                    outf[(size_t)row * D_MODEL + col] = v;
                } else {
                    int b = row >> 11, s = row & (S_LEN - 1);
                    int h = col >> 6, dh = col & 63;
                    outh[(((size_t)(b * N_HEADS + h)) * D_HEAD + dh) * S_LEN + s] = (bf16)v;
                }
            }
        }
    }
}

// ---------------- two-pass fused causal attention (write-once, swapped QK^T) ----------------
// grid: 1024 = 32 qx-slots x 32 bh. block: 256 (4 waves x 16 q-rows).
__global__ __launch_bounds__(256) void attn_fused(
    const bf16* __restrict__ Qh, const bf16* __restrict__ Kh, const bf16* __restrict__ VT,
    float* __restrict__ attn, bf16* __restrict__ ctx) {
    const int S = S_LEN, DH = D_HEAD;
    __shared__ bf16 Kls[64][80];
    __shared__ bf16 Vls[64][80];     // V^T tile: [dh][kj]
    __shared__ bf16 Pls[4][16][72];  // per-wave P tile: [q-row][k-col]
    __shared__ float rowinv[64];
    const int tid = threadIdx.x;
    const int lane = tid & 63, w = tid >> 6;
    const int g = lane >> 4, r16 = lane & 15;
    // balanced qt assignment: 4-term constant-sum permutation, heavy first
    const int id = blockIdx.x;
    const int bh = id & 31;
    const int qx = id >> 5;
    const int a = qx & 7, kq = qx >> 3;
    const int qt = (kq == 0) ? (31 - a) : (kq == 1) ? (16 + a) : (kq == 2) ? (15 - a) : a;
    const int q0 = qt * 64;
    const int qrow = q0 + w * 16 + r16;  // this lane's q-row (swapped layout)

    // Q fragment: lane l holds Q[q0 + w*16 + (l&15)][ (l>>4)*8 .. +7 ] per kk
    bf16x8 qa[2];
#pragma unroll
    for (int kk = 0; kk < 2; ++kk)
        qa[kk] = *(const bf16x8*)(Qh + (size_t)(bh * S + qrow) * DH + kk * 32 + g * 8);

    // ---- phase 1: row sums ----
    float rs = 0.f;
    for (int kt = 0; kt <= qt; ++kt) {
        __syncthreads();
#pragma unroll
        for (int sIt = 0; sIt < 2; ++sIt) {
            int slot = tid + sIt * 256;
            int srow = slot >> 3, c8 = (slot & 7) * 8;
            *(bf16x8*)&Kls[srow][c8] =
                *(const bf16x8*)(Kh + (size_t)(bh * S + kt * 64 + srow) * DH + c8);
        }
        __syncthreads();
#pragma unroll
        for (int n = 0; n < 4; ++n) {
            f32x4 s = {0.f, 0.f, 0.f, 0.f};
#pragma unroll
            for (int kk = 0; kk < 2; ++kk) {
                bf16x8 kb = *(const bf16x8*)&Kls[n * 16 + r16][kk * 32 + g * 8];
                s = __builtin_amdgcn_mfma_f32_16x16x32_bf16(kb, qa[kk], s, 0, 0, 0);
            }
            // lane holds cols kt*64 + n*16 + g*4 + r (r=0..3) of row qrow
            if (kt < qt) {
#pragma unroll
                for (int r = 0; r < 4; ++r) rs += __expf(s[r] * 0.125f);
            } else {
                int colb = kt * 64 + n * 16 + g * 4;
#pragma unroll
                for (int r = 0; r < 4; ++r)
                    rs += (colb + r <= qrow) ? __expf(s[r] * 0.125f) : 0.f;
            }
        }
    }
    rs += __shfl_xor(rs, 16);
    rs += __shfl_xor(rs, 32);
    const float inv = 1.f / rs;
    if (lane < 16) rowinv[w * 16 + lane] = inv;

    // ---- phase 2: recompute, write normalized attn, accumulate PV ----
    f32x4 oacc[4] = {};
    for (int kt = 0; kt <= qt; ++kt) {
        __syncthreads();
#pragma unroll
        for (int sIt = 0; sIt < 2; ++sIt) {
            int slot = tid + sIt * 256;
            int srow = slot >> 3, c8 = (slot & 7) * 8;
            *(bf16x8*)&Kls[srow][c8] =
                *(const bf16x8*)(Kh + (size_t)(bh * S + kt * 64 + srow) * DH + c8);
            *(bf16x8*)&Vls[srow][c8] =
                *(const bf16x8*)(VT + ((size_t)bh * DH + srow) * S + kt * 64 + c8);
        }
        __syncthreads();
#pragma unroll
        for (int n = 0; n < 4; ++n) {
            f32x4 s = {0.f, 0.f, 0.f, 0.f};
#pragma unroll
            for (int kk = 0; kk < 2; ++kk) {
                bf16x8 kb = *(const bf16x8*)&Kls[n * 16 + r16][kk * 32 + g * 8];
                s = __builtin_amdgcn_mfma_f32_16x16x32_bf16(kb, qa[kk], s, 0, 0, 0);
            }
            int colb = kt * 64 + n * 16 + g * 4;
            float p[4];
            if (kt < qt) {
#pragma unroll
                for (int r = 0; r < 4; ++r) p[r] = __expf(s[r] * 0.125f);
            } else {
#pragma unroll
                for (int r = 0; r < 4; ++r)
                    p[r] = (colb + r <= qrow) ? __expf(s[r] * 0.125f) : 0.f;
            }
            f32x4 pw = {p[0] * inv, p[1] * inv, p[2] * inv, p[3] * inv};
            *(f32x4*)(attn + (size_t)(bh * S + qrow) * S + colb) = pw;
            bf16x4 pb;
#pragma unroll
            for (int r = 0; r < 4; ++r) pb[r] = (bf16)p[r];
            *(bf16x4*)&Pls[w][r16][n * 16 + g * 4] = pb;
        }
        __syncthreads();
        // PV: oacc[d] += P(16x64) @ V(64x64)
#pragma unroll
        for (int d = 0; d < 4; ++d) {
#pragma unroll
            for (int kk = 0; kk < 2; ++kk) {
                bf16x8 pa = *(const bf16x8*)&Pls[w][r16][kk * 32 + g * 8];
                bf16x8 vb = *(const bf16x8*)&Vls[d * 16 + r16][kk * 32 + g * 8];
                oacc[d] = __builtin_amdgcn_mfma_f32_16x16x32_bf16(pa, vb, oacc[d], 0, 0, 0);
            }
        }
    }
    // ctx write: [B*S, D] bf16, rows g*4+r, col dh = d*16 + r16
    __syncthreads();
    const int b = bh >> 4, h = bh & 15;
    float invr[4];
#pragma unroll
    for (int r = 0; r < 4; ++r) invr[r] = rowinv[w * 16 + g * 4 + r];
#pragma unroll
    for (int d = 0; d < 4; ++d) {
#pragma unroll
        for (int r = 0; r < 4; ++r) {
            int srowg = q0 + w * 16 + g * 4 + r;
            ctx[(size_t)(b * S + srowg) * D_MODEL + h * D_HEAD + d * 16 + r16] =
                (bf16)(oacc[d][r] * invr[r]);
        }
    }
    // zero-fill fully-masked region (cols >= (qt+1)*64)
    int zstart = (qt + 1) * 64;
    for (int rr = 0; rr < 64; ++rr) {
        float* dst = attn + (size_t)(bh * S + q0 + rr) * S;
        for (int c = zstart + tid * 4; c < S; c += 1024) {
            f32x4 z = {0.f, 0.f, 0.f, 0.f};
            *(f32x4*)(dst + c) = z;
        }
    }
}

extern "C" void kernel_launch(void* const* d_in, const int* in_sizes, int n_in,
                              void* d_out, int out_size, void* d_ws, size_t ws_size,
                              hipStream_t stream) {
    const float* query = (const float*)d_in[0];
    const float* key   = (const float*)d_in[1];
    const float* value = (const float*)d_in[2];
    const float* Wq = (const float*)d_in[4];
    const float* bq = (const float*)d_in[5];
    const float* Wk = (const float*)d_in[6];
    const float* bk = (const float*)d_in[7];
    const float* Wv = (const float*)d_in[8];
    const float* bv = (const float*)d_in[9];
    const float* Wo = (const float*)d_in[10];
    const float* bo = (const float*)d_in[11];

    float* out  = (float*)d_out;                       // [4096,1024]
    float* attn = out + (size_t)M_ROWS * D_MODEL;      // [2,16,2048,2048]

    bf16* ws  = (bf16*)d_ws;
    const size_t MD = (size_t)M_ROWS * D_MODEL;   // 4M elems
    const size_t DD = (size_t)D_MODEL * D_MODEL;  // 1M elems
    bf16* Xq  = ws;
    bf16* Xk  = Xq + MD;
    bf16* Xv  = Xk + MD;
    bf16* WqT = Xv + MD;
    bf16* WkT = WqT + DD;
    bf16* WvT = WkT + DD;
    bf16* WoT = WvT + DD;
    bf16* Qh  = WoT + DD;
    bf16* Kh  = Qh + MD;
    bf16* VT  = Kh + MD;
    bf16* Ctx = VT + MD;

    int n = (int)MD;
    cvt_f32_bf16<<<2048, 256, 0, stream>>>(query, Xq, n);
    cvt_f32_bf16<<<2048, 256, 0, stream>>>(key, Xk, n);
    cvt_f32_bf16<<<2048, 256, 0, stream>>>(value, Xv, n);
    dim3 tg(32, 32);
    cvtT_f32_bf16<<<tg, 256, 0, stream>>>(Wq, WqT);
    cvtT_f32_bf16<<<tg, 256, 0, stream>>>(Wk, WkT);
    cvtT_f32_bf16<<<tg, 256, 0, stream>>>(Wv, WvT);
    cvtT_f32_bf16<<<tg, 256, 0, stream>>>(Wo, WoT);

    dim3 gg(M_ROWS / 128, D_MODEL / 128);
    gemm_bf16<<<gg, 256, 0, stream>>>(Xq, WqT, bq, Qh, nullptr, 0);
    gemm_bf16<<<gg, 256, 0, stream>>>(Xk, WkT, bk, Kh, nullptr, 0);
    gemm_bf16<<<gg, 256, 0, stream>>>(Xv, WvT, bv, VT, nullptr, 2);

    attn_fused<<<1024, 256, 0, stream>>>(Qh, Kh, VT, attn, Ctx);

    gemm_bf16<<<gg, 256, 0, stream>>>(Ctx, WoT, bo, nullptr, out, 1);
}